// Round 5
// baseline (275.378 us; speedup 1.0000x reference)
//
#include <hip/hip_runtime.h>
#include <hip/hip_bf16.h>
#include <stdint.h>

// Problem constants
#define NB    64
#define LSEQ  510
#define DIN   768
#define L1S   128
#define KS    20
#define OUTF  300
#define NPAD  320                 // padded out-features (5 x 64)
#define EPSL  1e-5f

#define M1    (NB * L1S)          // 8192
#define MK    (NB * KS)           // 1280
#define MT    (M1 + MK)           // 9472

// Output layout (flat, in return order, fp32)
#define OFF_H1    0
#define OFF_SCORE (M1 * OUTF)                 // 2,457,600
#define OFF_HK    (2 * M1 * OUTF)             // 4,915,200
#define OFF_SK    (OFF_HK + MK * OUTF)        // 5,299,200

// ws layout (bytes)
#define WS_FLAG    0
#define WS_SCORES  64            // float[MT]
#define WS_PROBS   40960         // float[64*128]
#define WS_WBF     81920         // ushort[320*768]  (bf16)

typedef short  short8_t  __attribute__((ext_vector_type(8)));
typedef float  float4v_t __attribute__((ext_vector_type(4)));
typedef unsigned short ushort4_t __attribute__((ext_vector_type(4)));

// LDS geometry for the fused kernel
#define SA_STRIDE 776            // shorts per A row (768 + 8 pad); 1552 B
#define SC_STRIDE 324            // floats per C row (320 + 4 pad)
#define LDS_BYTES 41984          // max(16*1552 + meta, 2*16*324*4 = 41472)

// ---------------------------------------------------------------------------
// Mask-representation detection (bool encoding undocumented). Scan the first
// 8192 bytes (valid under every candidate encoding of the (64,128) mask).
__global__ void detect_mask_kernel(const unsigned int* __restrict__ p, int* flag) {
    __shared__ int f_bf16, f_f32, f_other;
    if (threadIdx.x == 0) { f_bf16 = 0; f_f32 = 0; f_other = 0; }
    __syncthreads();
    for (int i = threadIdx.x; i < 2048; i += blockDim.x) {
        unsigned int v = p[i];
        if (v <= 1u) continue;
        if (v == 0x3F803F80u)       atomicOr(&f_bf16, 1);
        else if (v == 0x3F800000u)  atomicOr(&f_f32, 1);
        else                        atomicOr(&f_other, 1);
    }
    __syncthreads();
    if (threadIdx.x == 0) {
        int f = 0;
        if (f_bf16)       f = 3;
        else if (f_f32)   f = 2;
        else if (f_other) f = 1;
        *flag = f;
    }
}

__device__ inline bool mask_at(const void* m, int idx, int flag) {
    switch (flag) {
        case 1:  return ((const unsigned char*)m)[idx] != 0;
        case 2:  return ((const float*)m)[idx] != 0.0f;
        case 3:  return ((const unsigned short*)m)[idx] != 0;
        default: return ((const int*)m)[idx] != 0;
    }
}

// ---------------------------------------------------------------------------
// W (fp32 [300][768]) -> bf16 [320][768], rows 300..319 zero.
__global__ __launch_bounds__(256)
void wconv_kernel(const float* __restrict__ W, unsigned short* __restrict__ Wb) {
    int idx = blockIdx.x * 256 + threadIdx.x;     // 960 blocks, exact cover
    if (idx >= NPAD * DIN) return;
    int r = idx / DIN;
    float v = (r < OUTF) ? W[idx] : 0.f;          // idx == r*DIN + c
    __hip_bfloat16 b = __float2bfloat16(v);
    Wb[idx] = *(unsigned short*)&b;
}

// ---------------------------------------------------------------------------
// Fused: span-mean pool (global fp32 -> LDS bf16) + MFMA GEMM (split-K x2)
// + bias/LayerNorm/score epilogue.
// Block: 640 threads = 10 waves, owns 16 rows (spans) x 320 cols x full K.
// Wave w: col group cg = w%5 (cols 64*cg..+64), K half kh = w/5.
// Fragment layouts (verified round 3):
//   A: row = lane&15, k = (lane>>4)*8 + j   (8 contiguous bf16)
//   B: col = lane&15, k = (lane>>4)*8 + j   (W [out][in] row-major)
//   D: reg i -> row = (lane>>4)*4 + i, col = lane&15
__global__ __launch_bounds__(640, 5)
void fused_gemm_kernel(const float* __restrict__ t1,
                       const float* __restrict__ know,
                       const int* __restrict__ s1s, const int* __restrict__ s1e,
                       const int* __restrict__ kss, const int* __restrict__ kse,
                       const unsigned short* __restrict__ Wb,   // bf16 [320][768]
                       const float* __restrict__ bias,
                       const float* __restrict__ gamma,
                       const float* __restrict__ beta,
                       const float* __restrict__ Wsc,
                       const float* __restrict__ bsc,
                       float* __restrict__ out,
                       float* __restrict__ scores) {
    __shared__ unsigned long long lds_raw[LDS_BYTES / 8];
    unsigned short* sA   = (unsigned short*)lds_raw;            // [16][776]
    int*   sSrc = (int*)  ((char*)lds_raw + 16 * 1552);         // [16] float4 idx
    int*   sLen = (int*)  ((char*)lds_raw + 16 * 1552 + 64);    // [16]
    float* sInv = (float*)((char*)lds_raw + 16 * 1552 + 128);   // [16]

    const int tid = threadIdx.x;
    const int R0  = blockIdx.x * 16;
    const bool isk = (R0 >= M1);                 // uniform per block

    // ---- span metadata ----
    if (tid < 16) {
        int g = R0 + tid;
        int s, e, n;
        if (!isk) { n = g >> 7;          s = s1s[g];      e = s1e[g]; }
        else      { int gg = g - M1; n = gg / KS; s = kss[gg]; e = kse[gg]; }
        if (s < 0) s = 0;
        if (s > LSEQ - 4) s = LSEQ - 4;          // spec: s <= 505; defensive
        if (e > LSEQ) e = LSEQ;
        int len = e - s; if (len < 1) len = 1; if (len > 4) len = 4;
        sSrc[tid] = n * (LSEQ * (DIN / 4)) + s * (DIN / 4);
        sLen[tid] = len;
        sInv[tid] = 1.0f / (float)len;
    }
    __syncthreads();

    // ---- pooling: 16 spans x 192 float4-cols.  Rows s..s+3 always in
    // bounds (s <= 506), so issue 4 independent loads and mask the adds. ----
    const float4* src4 = (const float4*)(isk ? know : t1);
    for (int t = tid; t < 16 * 192; t += 640) {
        int sp = t / 192;
        int c4 = t - sp * 192;
        const float4* p = src4 + sSrc[sp] + c4;
        int len = sLen[sp];
        float4 v0 = p[0];
        float4 v1 = p[192];
        float4 v2 = p[2 * 192];
        float4 v3 = p[3 * 192];
        float f1 = (len > 1) ? 1.f : 0.f;
        float f2 = (len > 2) ? 1.f : 0.f;
        float f3 = (len > 3) ? 1.f : 0.f;
        float ax = v0.x + f1 * v1.x + f2 * v2.x + f3 * v3.x;
        float ay = v0.y + f1 * v1.y + f2 * v2.y + f3 * v3.y;
        float az = v0.z + f1 * v1.z + f2 * v2.z + f3 * v3.z;
        float aw = v0.w + f1 * v1.w + f2 * v2.w + f3 * v3.w;
        float inv = sInv[sp];
        __hip_bfloat16 b0 = __float2bfloat16(ax * inv);
        __hip_bfloat16 b1 = __float2bfloat16(ay * inv);
        __hip_bfloat16 b2 = __float2bfloat16(az * inv);
        __hip_bfloat16 b3 = __float2bfloat16(aw * inv);
        ushort4_t pk;
        pk.x = *(unsigned short*)&b0; pk.y = *(unsigned short*)&b1;
        pk.z = *(unsigned short*)&b2; pk.w = *(unsigned short*)&b3;
        *(ushort4_t*)(sA + sp * SA_STRIDE + c4 * 4) = pk;
    }
    __syncthreads();

    // ---- MFMA GEMM, split-K x2, 1-deep register double-buffer ----
    const int wave = tid >> 6;            // 0..9
    const int lane = tid & 63;
    const int quad = lane >> 4;
    const int l16  = lane & 15;
    const int cg   = wave % 5;            // col group: cols [64cg, 64cg+64)
    const int kh   = wave / 5;            // K half: [384kh, 384kh+384)
    const int BD   = 16 * DIN;

    const unsigned short* ap = sA + l16 * SA_STRIDE + quad * 8 + kh * 384;
    const unsigned short* bp = Wb + (size_t)(cg * 64 + l16) * DIN + quad * 8 + kh * 384;

    short8_t ac  = *(const short8_t*)(ap);
    short8_t b0c = *(const short8_t*)(bp);
    short8_t b1c = *(const short8_t*)(bp + BD);
    short8_t b2c = *(const short8_t*)(bp + 2 * BD);
    short8_t b3c = *(const short8_t*)(bp + 3 * BD);

    float4v_t acc0 = {0.f, 0.f, 0.f, 0.f};
    float4v_t acc1 = {0.f, 0.f, 0.f, 0.f};
    float4v_t acc2 = {0.f, 0.f, 0.f, 0.f};
    float4v_t acc3 = {0.f, 0.f, 0.f, 0.f};

#pragma unroll
    for (int it = 0; it < 12; ++it) {
        const int kn = ((it + 1) % 12) * 32;      // last iter reloads k=0 (unused)
        short8_t an  = *(const short8_t*)(ap + kn);
        short8_t b0n = *(const short8_t*)(bp + kn);
        short8_t b1n = *(const short8_t*)(bp + BD + kn);
        short8_t b2n = *(const short8_t*)(bp + 2 * BD + kn);
        short8_t b3n = *(const short8_t*)(bp + 3 * BD + kn);
        acc0 = __builtin_amdgcn_mfma_f32_16x16x32_bf16(ac, b0c, acc0, 0, 0, 0);
        acc1 = __builtin_amdgcn_mfma_f32_16x16x32_bf16(ac, b1c, acc1, 0, 0, 0);
        acc2 = __builtin_amdgcn_mfma_f32_16x16x32_bf16(ac, b2c, acc2, 0, 0, 0);
        acc3 = __builtin_amdgcn_mfma_f32_16x16x32_bf16(ac, b3c, acc3, 0, 0, 0);
        ac = an; b0c = b0n; b1c = b1n; b2c = b2n; b3c = b3n;
    }

    // ---- dump partials (sC aliases sA; all ds_reads of sA are complete) ----
    __syncthreads();
    float* sC = (float*)lds_raw;          // [2][16][SC_STRIDE]
#pragma unroll
    for (int i = 0; i < 4; ++i) {
        int r = (kh * 16 + quad * 4 + i) * SC_STRIDE + cg * 64 + l16;
        sC[r +  0] = acc0[i];
        sC[r + 16] = acc1[i];
        sC[r + 32] = acc2[i];
        sC[r + 48] = acc3[i];
    }
    __syncthreads();

    // ---- epilogue: bias + LayerNorm + score.  Waves 0..7, 2 rows each ----
    if (wave < 8) {
        const float bs0 = bsc[0];
#pragma unroll
        for (int rr = 0; rr < 2; ++rr) {
            const int r = wave * 2 + rr;
            const int g = R0 + r;
            float tv[5];
            float s = 0.f;
#pragma unroll
            for (int m = 0; m < 5; ++m) {
                int c = lane + 64 * m;
                float v = 0.f;
                if (c < OUTF)
                    v = sC[r * SC_STRIDE + c] + sC[(16 + r) * SC_STRIDE + c] + bias[c];
                tv[m] = v; s += v;
            }
#pragma unroll
            for (int off = 32; off > 0; off >>= 1) s += __shfl_xor(s, off, 64);
            const float mean = s * (1.0f / OUTF);
            float vs = 0.f;
#pragma unroll
            for (int m = 0; m < 5; ++m) {
                int c = lane + 64 * m;
                float d = (c < OUTF) ? (tv[m] - mean) : 0.f;
                vs += d * d;
            }
#pragma unroll
            for (int off = 32; off > 0; off >>= 1) vs += __shfl_xor(vs, off, 64);
            const float rstd = rsqrtf(vs * (1.0f / OUTF) + EPSL);

            const size_t off0 = isk ? (size_t)OFF_HK + (size_t)(g - M1) * OUTF
                                    : (size_t)g * OUTF;
            float sc = 0.f;
#pragma unroll
            for (int m = 0; m < 5; ++m) {
                int c = lane + 64 * m;
                if (c < OUTF) {
                    float h = (tv[m] - mean) * rstd * gamma[c] + beta[c];
                    out[off0 + c] = h;
                    sc += h * Wsc[c];
                }
            }
#pragma unroll
            for (int off = 32; off > 0; off >>= 1) sc += __shfl_xor(sc, off, 64);
            if (lane == 0) scores[g] = sc + bs0;
        }
    }
}

// ---------------------------------------------------------------------------
// Masked softmax: 128 waves (32 blocks).  Waves 0..63: branch1 row -> probs ws.
// Waves 64..127: know row -> sk written directly to out.
__global__ __launch_bounds__(256)
void softmax_kernel(const float* __restrict__ scores,
                    const void* __restrict__ m1,
                    const void* __restrict__ mk,
                    const int* __restrict__ flagp,
                    float* __restrict__ probs,
                    float* __restrict__ out) {
    const int flag = *flagp;
    const int w = blockIdx.x * 4 + (threadIdx.x >> 6);
    const int lane = threadIdx.x & 63;

    if (w < NB) {
        const int n = w;
        float v0 = scores[n * L1S + lane];
        float v1 = scores[n * L1S + lane + 64];
        if (mask_at(m1, n * L1S + lane, flag))      v0 = -INFINITY;
        if (mask_at(m1, n * L1S + lane + 64, flag)) v1 = -INFINITY;
        float mx = fmaxf(v0, v1);
#pragma unroll
        for (int off = 32; off > 0; off >>= 1) mx = fmaxf(mx, __shfl_xor(mx, off, 64));
        float e0 = __expf(v0 - mx);
        float e1 = __expf(v1 - mx);
        float s = e0 + e1;
#pragma unroll
        for (int off = 32; off > 0; off >>= 1) s += __shfl_xor(s, off, 64);
        float inv = 1.0f / s;
        probs[n * L1S + lane]      = e0 * inv;
        probs[n * L1S + lane + 64] = e1 * inv;
    } else {
        const int n = w - NB;
        float v = -INFINITY;
        if (lane < KS) {
            v = scores[M1 + n * KS + lane];
            if (mask_at(mk, n * KS + lane, flag)) v = -INFINITY;
        }
        float mx = v;
#pragma unroll
        for (int off = 32; off > 0; off >>= 1) mx = fmaxf(mx, __shfl_xor(mx, off, 64));
        float e = (lane < KS) ? __expf(v - mx) : 0.f;
        float s = e;
#pragma unroll
        for (int off = 32; off > 0; off >>= 1) s += __shfl_xor(s, off, 64);
        if (lane < KS) out[(size_t)OFF_SK + n * KS + lane] = e / s;
    }
}

// ---------------------------------------------------------------------------
// Broadcast probs (64x128) -> out score region (64,128,300), float4 writes.
__global__ __launch_bounds__(256)
void bcast_kernel(const float* __restrict__ probs, float* __restrict__ out) {
    const int e0 = (blockIdx.x * 256 + threadIdx.x) * 4;   // 2400 blocks exact
    float4 v;
    v.x = probs[(e0 + 0) / OUTF];
    v.y = probs[(e0 + 1) / OUTF];
    v.z = probs[(e0 + 2) / OUTF];
    v.w = probs[(e0 + 3) / OUTF];
    *(float4*)(out + (size_t)OFF_SCORE + e0) = v;
}

// ---------------------------------------------------------------------------
extern "C" void kernel_launch(void* const* d_in, const int* in_sizes, int n_in,
                              void* d_out, int out_size, void* d_ws, size_t ws_size,
                              hipStream_t stream) {
    const float* t1   = (const float*)d_in[0];
    const float* know = (const float*)d_in[1];
    const int* s1s = (const int*)d_in[2];
    const int* s1e = (const int*)d_in[3];
    const void* m1 = d_in[4];
    const int* kss = (const int*)d_in[5];
    const int* kse = (const int*)d_in[6];
    const void* mk = d_in[7];
    const float* Wl  = (const float*)d_in[8];
    const float* bl  = (const float*)d_in[9];
    const float* gm  = (const float*)d_in[10];
    const float* bt  = (const float*)d_in[11];
    const float* Wsc = (const float*)d_in[12];
    const float* bsc = (const float*)d_in[13];
    float* out = (float*)d_out;

    char* ws = (char*)d_ws;
    int*            flag   = (int*)(ws + WS_FLAG);
    float*          scores = (float*)(ws + WS_SCORES);
    float*          probs  = (float*)(ws + WS_PROBS);
    unsigned short* Wb     = (unsigned short*)(ws + WS_WBF);

    detect_mask_kernel<<<1, 256, 0, stream>>>((const unsigned int*)m1, flag);
    wconv_kernel<<<(NPAD * DIN + 255) / 256, 256, 0, stream>>>(Wl, Wb);
    fused_gemm_kernel<<<MT / 16, 640, 0, stream>>>(t1, know, s1s, s1e, kss, kse,
                                                   Wb, bl, gm, bt, Wsc, bsc,
                                                   out, scores);
    softmax_kernel<<<32, 256, 0, stream>>>(scores, m1, mk, flag, probs, out);
    bcast_kernel<<<(M1 * OUTF) / 1024, 256, 0, stream>>>(probs, out);
}